// Round 7
// baseline (59.789 us; speedup 1.0000x reference)
//
#include <hip/hip_runtime.h>

#define DIM 4096

constexpr float LOG2E = 1.44269504088896340736f;
constexpr float TWO_LOG2E = 2.0f * LOG2E;

struct Params {
  float wf, uf, bf;   // pre-scaled by log2e
  float wi, ui, bi;   // pre-scaled by log2e
  float wc, uc, bc;   // pre-scaled by 2*log2e  (tanh uses e^{-2z} = 2^{-2z*log2e})
  float wo, uo, bo;   // pre-scaled by log2e
};

__device__ __forceinline__ float frcp(float x) { return __builtin_amdgcn_rcpf(x); }
__device__ __forceinline__ float fexp2(float x) { return __builtin_amdgcn_exp2f(x); }

// sigma(z1)+sigma(z2), args pre-scaled by log2e. Exact identity:
//   (2+e1+e2) / ((1+e1)(1+e2)),  e=2^-u.  2 exp2 + 1 rcp.
__device__ __forceinline__ float sig_sum2(float u1, float u2) {
  float e1 = fexp2(-u1);
  float e2 = fexp2(-u2);
  float s1 = 1.0f + e1;
  float den = fmaf(s1, e2, s1);        // (1+e1)(1+e2)
  float num = (2.0f + e1) + e2;
  return num * frcp(den);
}

// sigma(zi)*tanh(zg): ui = zi*log2e, ug = 2*zg*log2e. Exact identity:
//   (1-eg) / ((1+ei)(1+eg)).  2 exp2 + 1 rcp.  eg clamped at 2^60.
__device__ __forceinline__ float sig_mul_tanh(float ui, float ug) {
  float ei = fexp2(-ui);
  float eg = fexp2(fminf(-ug, 60.0f));
  float si = 1.0f + ei;
  float den = fmaf(si, eg, si);        // (1+ei)(1+eg)
  float num = 1.0f - eg;
  return num * frcp(den);
}

__device__ __forceinline__ float leaf_node(float x, const Params& p) {
  // h_sum = 0: ct = [ (1-eg)(1+ef) + (1+ei)(1+eg) ] / [ (1+ef)(1+ei)(1+eg) ]
  float af = fmaf(p.wf, x, p.bf);
  float ai = fmaf(p.wi, x, p.bi);
  float ag = fmaf(p.wc, x, p.bc);
  float ef = fexp2(-af);
  float ei = fexp2(-ai);
  float eg = fexp2(fminf(-ag, 60.0f));
  float sf = 1.0f + ef;
  float si = 1.0f + ei;
  float t1 = fmaf(si, eg, si);                 // (1+ei)(1+eg)
  float den = t1 * sf;
  float num = fmaf(1.0f - eg, sf, t1);
  float ct = num * frcp(den);
  return sig_mul_tanh(fmaf(p.wo, x, p.bo), ct * TWO_LOG2E);
}

__device__ __forceinline__ float inner_node(float x, float hl, float hr,
                                            const Params& p, float& ct_out) {
  float hs = hl + hr;
  float af = fmaf(p.wf, x, p.bf);
  float fsum = sig_sum2(fmaf(p.uf, hl, af), fmaf(p.uf, hr, af));
  float itgt = sig_mul_tanh(fmaf(p.ui, hs, fmaf(p.wi, x, p.bi)),
                            fmaf(p.uc, hs, fmaf(p.wc, x, p.bc)));
  float ct = itgt + fsum;
  ct_out = ct;
  // |ct| <= 3 so the tanh arg never needs clamping.
  return sig_mul_tanh(fmaf(p.uo, hs, fmaf(p.wo, x, p.bo)), ct * TWO_LOG2E);
}

// Breadth-first depth-3 tile rooted at level-9 node r (covers 15 nodes:
// 8 leaves at L12, 4 at L11, 2 at L10, r at L9). All 15 row loads issued
// up front; 8 independent leaf chains expose in-wave ILP to hide both
// load latency and the serial fma->exp2->rcp gate chains.
__device__ __forceinline__ float sub8(const float* __restrict__ tvd, int r,
                                      const Params& p) {
  const float* lp = tvd + (size_t)(8 * r + 7) * DIM;      // leaves 8r+7..8r+14
  float x0 = lp[0];
  float x1 = lp[DIM];
  float x2 = lp[2 * DIM];
  float x3 = lp[3 * DIM];
  float x4 = lp[4 * (size_t)DIM];
  float x5 = lp[5 * (size_t)DIM];
  float x6 = lp[6 * (size_t)DIM];
  float x7 = lp[7 * (size_t)DIM];
  const float* mp = tvd + (size_t)(4 * r + 3) * DIM;      // L11: 4r+3..4r+6
  float xm0 = mp[0];
  float xm1 = mp[DIM];
  float xm2 = mp[2 * DIM];
  float xm3 = mp[3 * DIM];
  const float* np = tvd + (size_t)(2 * r + 1) * DIM;      // L10: 2r+1, 2r+2
  float xn0 = np[0];
  float xn1 = np[DIM];
  float xr = tvd[(size_t)r * DIM];                        // L9: r

  float L0 = leaf_node(x0, p);
  float L1 = leaf_node(x1, p);
  float L2 = leaf_node(x2, p);
  float L3 = leaf_node(x3, p);
  float L4 = leaf_node(x4, p);
  float L5 = leaf_node(x5, p);
  float L6 = leaf_node(x6, p);
  float L7 = leaf_node(x7, p);
  float dct;
  float M0 = inner_node(xm0, L0, L1, p, dct);
  float M1 = inner_node(xm1, L2, L3, p, dct);
  float M2 = inner_node(xm2, L4, L5, p, dct);
  float M3 = inner_node(xm3, L6, L7, p, dct);
  float N0 = inner_node(xn0, M0, M1, p, dct);
  float N1 = inner_node(xn1, M2, M3, p, dct);
  return inner_node(xr, N0, N1, p, dct);
}

__device__ __forceinline__ Params load_params(
    int d,
    const float* wf, const float* uf, const float* bf,
    const float* wi, const float* ui, const float* bi,
    const float* wc, const float* uc, const float* bc,
    const float* wo, const float* uo, const float* bo) {
  Params p;
  p.wf = wf[d] * LOG2E;     p.uf = uf[d] * LOG2E;     p.bf = bf[d] * LOG2E;
  p.wi = wi[d] * LOG2E;     p.ui = ui[d] * LOG2E;     p.bi = bi[d] * LOG2E;
  p.wc = wc[d] * TWO_LOG2E; p.uc = uc[d] * TWO_LOG2E; p.bc = bc[d] * TWO_LOG2E;
  p.wo = wo[d] * LOG2E;     p.uo = uo[d] * LOG2E;     p.bo = bo[d] * LOG2E;
  return p;
}

// Phase 1: 128 subtrees (roots at level 7) x 16 channel-blocks, 256 thr/block,
// 1 channel/thread. Levels 12..7 (63 nodes) via 4x sub8 + 3 inner nodes.
// (256,6): cap ~85 VGPR / 6 waves per SIMD -- room for the 15-load batches.
__global__ __launch_bounds__(256, 6) void treelstm_p1(
    const float* __restrict__ tv,
    const float* __restrict__ wf, const float* __restrict__ uf, const float* __restrict__ bf,
    const float* __restrict__ wi, const float* __restrict__ ui, const float* __restrict__ bi,
    const float* __restrict__ wc, const float* __restrict__ uc, const float* __restrict__ bc,
    const float* __restrict__ wo, const float* __restrict__ uo, const float* __restrict__ bo,
    float* __restrict__ ws) {
  const int cb = blockIdx.x & 15;          // channel block
  const int g  = blockIdx.x >> 4;          // subtree index 0..127
  const int d  = cb * 256 + threadIdx.x;   // channel
  const float* tvd = tv + d;

  const Params p = load_params(d, wf, uf, bf, wi, ui, bi, wc, uc, bc, wo, uo, bo);

  // level-9 descendants of root 127+g: 511+4g .. 514+4g
  float h9_0 = sub8(tvd, 511 + 4 * g, p);
  float h9_1 = sub8(tvd, 512 + 4 * g, p);
  float h9_2 = sub8(tvd, 513 + 4 * g, p);
  float h9_3 = sub8(tvd, 514 + 4 * g, p);

  float dct;
  float x8a = tvd[(size_t)(255 + 2 * g) * DIM];
  float x8b = tvd[(size_t)(256 + 2 * g) * DIM];
  float h8a = inner_node(x8a, h9_0, h9_1, p, dct);
  float h8b = inner_node(x8b, h9_2, h9_3, p, dct);
  float x7 = tvd[(size_t)(127 + g) * DIM];
  float h7 = inner_node(x7, h8a, h8b, p, dct);

  ws[(size_t)g * DIM + d] = h7;
}

// Phase 2: levels 6..0 from staged h7 (DFS; only 127 nodes total per channel).
template <int LVL>
__device__ __forceinline__ float top_h(const float* __restrict__ tvd,
                                       const float* __restrict__ wsd, int node,
                                       const Params& p, float& ct_out) {
  if constexpr (LVL == 7) {
    ct_out = 0.0f;  // never consumed at this level
    return wsd[(size_t)(node - 127) * DIM];
  } else {
    float cl, cr;
    float hl = top_h<LVL + 1>(tvd, wsd, 2 * node + 1, p, cl);
    float hr = top_h<LVL + 1>(tvd, wsd, 2 * node + 2, p, cr);
    float x = tvd[(size_t)node * DIM];
    return inner_node(x, hl, hr, p, ct_out);
  }
}

// 16 blocks x 256 threads = 4096 threads (one per channel).
__global__ __launch_bounds__(256) void treelstm_p2(
    const float* __restrict__ tv,
    const float* __restrict__ wf, const float* __restrict__ uf, const float* __restrict__ bf,
    const float* __restrict__ wi, const float* __restrict__ ui, const float* __restrict__ bi,
    const float* __restrict__ wc, const float* __restrict__ uc, const float* __restrict__ bc,
    const float* __restrict__ wo, const float* __restrict__ uo, const float* __restrict__ bo,
    const float* __restrict__ ws, float* __restrict__ out) {
  const int d = blockIdx.x * 256 + threadIdx.x;

  const Params p = load_params(d, wf, uf, bf, wi, ui, bi, wc, uc, bc, wo, uo, bo);

  float ct;
  float h = top_h<0>(tv + d, ws + d, 0, p, ct);
  out[d] = h;
  out[DIM + d] = ct;
}

extern "C" void kernel_launch(void* const* d_in, const int* in_sizes, int n_in,
                              void* d_out, int out_size, void* d_ws, size_t ws_size,
                              hipStream_t stream) {
  const float* tv = (const float*)d_in[0];
  // d_in[1] = depth (int, 13) -- structure hard-coded to depth 13.
  const float* wf = (const float*)d_in[2];
  const float* uf = (const float*)d_in[3];
  const float* bf = (const float*)d_in[4];
  const float* wi = (const float*)d_in[5];
  const float* ui = (const float*)d_in[6];
  const float* bi = (const float*)d_in[7];
  const float* wc = (const float*)d_in[8];
  const float* uc = (const float*)d_in[9];
  const float* bc = (const float*)d_in[10];
  const float* wo = (const float*)d_in[11];
  const float* uo = (const float*)d_in[12];
  const float* bo = (const float*)d_in[13];

  float* ws = (float*)d_ws;   // 128 * 4096 * 4 B = 2 MiB (ws_size verified >= 2 MiB in rounds 2-6)
  float* out = (float*)d_out; // 8192 floats: h then c

  treelstm_p1<<<dim3(128 * 16), dim3(256), 0, stream>>>(
      tv, wf, uf, bf, wi, ui, bi, wc, uc, bc, wo, uo, bo, ws);

  treelstm_p2<<<dim3(16), dim3(256), 0, stream>>>(
      tv, wf, uf, bf, wi, ui, bi, wc, uc, bc, wo, uo, bo, ws, out);
}